// Round 14
// baseline (75.406 us; speedup 1.0000x reference)
//
#include <hip/hip_runtime.h>

#define ISZ 128
#define HW (ISZ * ISZ)
#define TSZ 4
#define NEARP 0.1f
#define FARP 100.0f
#define EPSF 1e-9f
#define TILE 8
#define NTJ (ISZ / TILE)     // 16 tiles per row
#define NTILES (NTJ * NTJ)   // 256 tiles per image
#define SPLIT 4              // face-range splits per tile
#define SPLIT_LOG 2

// d_ws layout:
//   float4 bbox[B*F]                  (umin,umax,vmin,vmax)      32 KB
//   float4 data[B*F*4]                4-float4 face record      128 KB
//   u64    keys[B*HW]                 (zp_bits<<32)|face        256 KB
// data record:
//   d0 = {c00, c01, c02, c10}
//   d1 = {c11, c12, c20, c21}
//   d2 = {c22, z0,  z1,  z2 }
//   d3 = {light, 0, 0, 0}   (only resolve reads d3)

__global__ void face_pre(const float* __restrict__ T,
                         const float* __restrict__ verts,
                         const int* __restrict__ faces,
                         const float* __restrict__ Km,
                         const float* __restrict__ dist,
                         float4* __restrict__ bbox,
                         float4* __restrict__ data,
                         unsigned long long* __restrict__ keys,
                         int B, int V, int F) {
#pragma clang fp contract(off)
    int t = blockIdx.x * blockDim.x + threadIdx.x;

    // fused keys init (grid-stride): sentinel = no hit
    int nk = B * HW;
    int stride = gridDim.x * blockDim.x;
    for (int q = t; q < nk; q += stride) keys[q] = 0xFFFFFFFFFFFFFFFFull;

    if (t >= B * F) return;
    int b = t / F, f = t - b * F;

    const float* Tb = T + b * 16;
    const float* Kb = Km + b * 9;
    const float* Db = dist + b * 5;
    float k1 = Db[0], k2 = Db[1], p1 = Db[2], p2 = Db[3], k3 = Db[4];

    int idx0 = faces[((size_t)b * F + f) * 3 + 0];
    int idx1 = faces[((size_t)b * F + f) * 3 + 1];
    int idx2 = faces[((size_t)b * F + f) * 3 + 2];
    int idx[3] = {idx0, idx1, idx2};

    float P[3][3];
    for (int k = 0; k < 3; ++k) {
        const float* vp = verts + ((size_t)b * V + idx[k]) * 3;
        P[k][0] = vp[0]; P[k][1] = vp[1]; P[k][2] = vp[2];
    }

    // ---- lighting: n = cross(v12, v10), normalized; cos = relu(n_y) ----
    float v10x = P[0][0] - P[1][0], v10y = P[0][1] - P[1][1], v10z = P[0][2] - P[1][2];
    float v12x = P[2][0] - P[1][0], v12y = P[2][1] - P[1][1], v12z = P[2][2] - P[1][2];
    float nx = v12y * v10z - v12z * v10y;
    float ny = v12z * v10x - v12x * v10z;
    float nz = v12x * v10y - v12y * v10x;
    float norm = sqrtf((nx * nx + ny * ny) + nz * nz);
    float cosv = ny / (norm + EPSF);
    cosv = fmaxf(cosv, 0.0f);
    float light = 0.5f + 0.5f * cosv;

    // ---- project the 3 vertices (exact reference op order) ----
    float xs[3], ys[3], zs[3];
    for (int k = 0; k < 3; ++k) {
        float X = P[k][0], Y = P[k][1], Z = P[k][2];
        float vcx = ((Tb[0] * X + Tb[1] * Y) + Tb[2] * Z) + Tb[3];
        float vcy = ((Tb[4] * X + Tb[5] * Y) + Tb[6] * Z) + Tb[7];
        float vcz = ((Tb[8] * X + Tb[9] * Y) + Tb[10] * Z) + Tb[11];
        float zq = vcz + EPSF;
        float x_ = vcx / zq;
        float y_ = vcy / zq;
        float r2 = x_ * x_ + y_ * y_;
        float rad = ((1.0f + k1 * r2) + (k2 * r2) * r2) + ((k3 * r2) * r2) * r2;
        float xd = (x_ * rad + ((2.0f * p1) * x_) * y_) + p2 * (r2 + (2.0f * x_) * x_);
        float yd = (y_ * rad + p1 * (r2 + (2.0f * y_) * y_)) + ((2.0f * p2) * x_) * y_;
        float pixx = (Kb[0] * xd + Kb[1] * yd) + Kb[2];
        float pixy = (Kb[3] * xd + Kb[4] * yd) + Kb[5];
        float u = (2.0f * (pixx - (float)ISZ / 2.0f)) / (float)ISZ;
        float v = (2.0f * (((float)ISZ - pixy) - (float)ISZ / 2.0f)) / (float)ISZ;
        xs[k] = u; ys[k] = v; zs[k] = vcz;
    }

    float x0 = xs[0], x1 = xs[1], x2 = xs[2];
    float y0 = ys[0], y1 = ys[1], y2 = ys[2];

    float det = (x0 * (y1 - y2) + x1 * (y2 - y0)) + x2 * (y0 - y1);
    bool degen = fabsf(det) < 1e-6f;
    if (degen) det = 1e-6f;

    float c00 = (y1 - y2) / det, c01 = (x2 - x1) / det, c02 = (x1 * y2 - x2 * y1) / det;
    float c10 = (y2 - y0) / det, c11 = (x0 - x2) / det, c12 = (x2 * y0 - x0 * y2) / det;
    float c20 = (y0 - y1) / det, c21 = (x1 - x0) / det, c22 = (x0 * y1 - x1 * y0) / det;

    float umin, umax, vmin, vmax;
    if (degen) {
        // clamped-det faces rasterize as an unbounded thin band: test everywhere.
        umin = -1e30f; umax = 1e30f; vmin = -1e30f; vmax = 1e30f;
    } else {
        umin = fminf(fminf(x0, x1), x2) - 1e-3f;
        umax = fmaxf(fmaxf(x0, x1), x2) + 1e-3f;
        vmin = fminf(fminf(y0, y1), y2) - 1e-3f;
        vmax = fmaxf(fmaxf(y0, y1), y2) + 1e-3f;
    }

    bbox[t] = make_float4(umin, umax, vmin, vmax);
    float4* dp = data + (size_t)t * 4;
    dp[0] = make_float4(c00, c01, c02, c10);
    dp[1] = make_float4(c11, c12, c20, c21);
    dp[2] = make_float4(c22, zs[0], zs[1], zs[2]);
    dp[3] = make_float4(light, 0.0f, 0.0f, 0.0f);
}

// broadcast lane `l`'s value to all lanes (l is wave-uniform) — v_readlane,
// 1-cycle VALU->SGPR, no memory.
__device__ __forceinline__ float rl(float v, int l) {
    return __int_as_float(__builtin_amdgcn_readlane(__float_as_int(v), l));
}

// One wave (64 threads = 64 pixels) per (8x8 tile, face-split). Per 64-face
// chunk: lane l holds face (base+l)'s bbox + 12-float record in REGISTERS
// (coalesced float4 loads, unconditional). Lane-test bbox vs tile rect ->
// ballot -> uniform mask; iterate set bits fetching the candidate's record
// via 12 v_readlane broadcasts — ZERO memory ops in the scan loop. Depth min
// kept as register u64 key (zp_bits<<32)|face (bit-monotone for positive
// floats => exact lexicographic (zp,face) min == np.argmin first-occurrence).
// ONE atomicMin per lane at the end combines the SPLIT partials.
__global__ __launch_bounds__(64) void raster_scan(
        const float4* __restrict__ bbox,
        const float4* __restrict__ data,
        unsigned long long* __restrict__ keys,
        int B, int F) {
#pragma clang fp contract(off)
    int blk = blockIdx.x;
    int fs = blk & (SPLIT - 1);
    int t2 = blk >> SPLIT_LOG;
    int b = t2 / NTILES, tile = t2 - b * NTILES;
    int ti = tile / NTJ, tj = tile - ti * NTJ;
    int lane = threadIdx.x;
    int li = lane / TILE, lj = lane - li * TILE;
    int i = ti * TILE + li;
    int j = tj * TILE + lj;

    float px = (float)(2 * j + 1 - ISZ) / (float)ISZ;
    float py = (float)(2 * i + 1 - ISZ) / (float)ISZ;
    float pxmin = (float)(2 * (tj * TILE) + 1 - ISZ) / (float)ISZ;
    float pxmax = (float)(2 * (tj * TILE + TILE - 1) + 1 - ISZ) / (float)ISZ;
    float pymin = (float)(2 * (ti * TILE) + 1 - ISZ) / (float)ISZ;
    float pymax = (float)(2 * (ti * TILE + TILE - 1) + 1 - ISZ) / (float)ISZ;

    const float4* bb_b = bbox + (size_t)b * F;
    const float4* dt_b = data + (size_t)b * F * 4;

    int nch = (F + 63) >> 6;                 // 64-face chunks
    int cpB = (nch + SPLIT - 1) / SPLIT;     // chunks per split

    unsigned long long bestkey = 0xFFFFFFFFFFFFFFFFull;

    for (int it = 0; it < cpB; ++it) {
        int ci = fs * cpB + it;
        if (ci >= nch) break;                // uniform
        int f = (ci << 6) + lane;
        int fl = min(f, F - 1);              // clamp for safe load; mask uses real f
        // coalesced chunk load: lane l holds face (base+l)'s record
        float4 r  = bb_b[fl];
        const float4* dp = dt_b + (size_t)fl * 4;
        float4 d0 = dp[0], d1 = dp[1], d2 = dp[2];

        bool pass = (f < F) &
                    (r.x <= pxmax) & (r.y >= pxmin) & (r.z <= pymax) & (r.w >= pymin);
        unsigned long long m = __ballot(pass);   // uniform (SGPR)

        while (m) {
            int bit = __ffsll((unsigned long long)m) - 1;
            m &= m - 1;
            int fc = (ci << 6) + bit;            // uniform face index
            // 12 readlane broadcasts from lane `bit` — no memory
            float c00 = rl(d0.x, bit), c01 = rl(d0.y, bit), c02 = rl(d0.z, bit);
            float c10 = rl(d0.w, bit), c11 = rl(d1.x, bit), c12 = rl(d1.y, bit);
            float c20 = rl(d1.z, bit), c21 = rl(d1.w, bit), c22 = rl(d2.x, bit);
            float z0  = rl(d2.y, bit), z1  = rl(d2.z, bit), z2  = rl(d2.w, bit);

            float w0 = (c00 * px + c01 * py) + c02;
            float w1 = (c10 * px + c11 * py) + c12;
            float w2 = (c20 * px + c21 * py) + c22;
            bool inside = (w0 >= 0.0f) & (w0 <= 1.0f) &
                          (w1 >= 0.0f) & (w1 <= 1.0f) &
                          (w2 >= 0.0f) & (w2 <= 1.0f);
            if (__any(inside)) {
                float s = ((w0 / z0) + (w1 / z1)) + (w2 / z2);
                float zp = 1.0f / s;
                bool ok = inside & (zp > NEARP) & (zp < FARP);
                unsigned long long key =
                    ((unsigned long long)__float_as_uint(zp) << 32) | (unsigned)fc;
                if (ok && key < bestkey) bestkey = key;   // cndmask, no branch
            }
        }
    }

    if (bestkey != 0xFFFFFFFFFFFFFFFFull) {
        int p = i * ISZ + j;
        atomicMin(&keys[(size_t)b * HW + p], bestkey);
    }
}

// One thread per pixel: read winning (zp,face), recompute shading with
// bit-identical ops (same inputs -> same IEEE results as the raster pass).
__global__ __launch_bounds__(256) void resolve(
        const unsigned long long* __restrict__ keys,
        const float4* __restrict__ data,
        const float* __restrict__ tex,
        float* __restrict__ out,
        int B, int F) {
#pragma clang fp contract(off)
    int t = blockIdx.x * blockDim.x + threadIdx.x;
    if (t >= B * HW) return;
    int b = t / HW, p = t - b * HW;
    int i = p / ISZ, j = p - i * ISZ;

    unsigned long long key = keys[t];
    float o0 = 0.0f, o1 = 0.0f, o2 = 0.0f;
    if (key != 0xFFFFFFFFFFFFFFFFull) {
        int f = (int)(unsigned)(key & 0xFFFFFFFFull);
        const float4* dp = data + ((size_t)b * F + f) * 4;
        float4 d0 = dp[0], d1 = dp[1], d2 = dp[2], d3 = dp[3];
        float px = (float)(2 * j + 1 - ISZ) / (float)ISZ;
        float py = (float)(2 * i + 1 - ISZ) / (float)ISZ;
        float w0 = (d0.x * px + d0.y * py) + d0.z;
        float w1 = (d0.w * px + d1.x * py) + d1.y;
        float w2 = (d1.z * px + d1.w * py) + d2.x;
        float z0 = d2.y, z1 = d2.z, z2 = d2.w;
        float s = ((w0 / z0) + (w1 / z1)) + (w2 / z2);
        float zp = 1.0f / s;

        float wp0 = (w0 / z0) * zp;
        float wp1 = (w1 / z1) * zp;
        float wp2 = (w2 / z2) * zp;
        wp0 = fminf(fmaxf(wp0, 0.0f), 1.0f);
        wp1 = fminf(fmaxf(wp1, 0.0f), 1.0f);
        wp2 = fminf(fmaxf(wp2, 0.0f), 1.0f);
        float ssum = ((wp0 + wp1) + wp2) + EPSF;
        wp0 = wp0 / ssum; wp1 = wp1 / ssum; wp2 = wp2 / ssum;
        int t0 = min(max((int)floorf(wp0 * (float)TSZ), 0), TSZ - 1);
        int t1 = min(max((int)floorf(wp1 * (float)TSZ), 0), TSZ - 1);
        int t2c = min(max((int)floorf(wp2 * (float)TSZ), 0), TSZ - 1);
        float light = d3.x;
        const float* tp = tex + ((((((size_t)b * F + f) * TSZ + t0) * TSZ + t1) * TSZ + t2c) * 3);
        o0 = tp[0] * light;
        o1 = tp[1] * light;
        o2 = tp[2] * light;
    }

    out[((size_t)b * 3 + 0) * HW + p] = o0;
    out[((size_t)b * 3 + 1) * HW + p] = o1;
    out[((size_t)b * 3 + 2) * HW + p] = o2;
}

extern "C" void kernel_launch(void* const* d_in, const int* in_sizes, int n_in,
                              void* d_out, int out_size, void* d_ws, size_t ws_size,
                              hipStream_t stream) {
    const float* T     = (const float*)d_in[0];
    const float* verts = (const float*)d_in[1];
    const int*   faces = (const int*)d_in[2];
    const float* tex   = (const float*)d_in[3];
    const float* Km    = (const float*)d_in[4];
    const float* dist  = (const float*)d_in[5];

    int B = in_sizes[0] / 16;
    int V = in_sizes[1] / (3 * B);
    int F = in_sizes[2] / (3 * B);

    float4* bbox = (float4*)d_ws;                        // B*F float4
    float4* data = bbox + (size_t)B * F;                 // B*F*4 float4
    unsigned long long* keys =
        (unsigned long long*)(data + (size_t)B * F * 4); // B*HW u64

    int nfaces = B * F;
    face_pre<<<(nfaces + 255) / 256, 256, 0, stream>>>(T, verts, faces, Km, dist,
                                                       bbox, data, keys, B, V, F);

    raster_scan<<<B * NTILES * SPLIT, 64, 0, stream>>>(bbox, data, keys, B, F);

    int npix = B * HW;
    resolve<<<(npix + 255) / 256, 256, 0, stream>>>(keys, data, tex,
                                                    (float*)d_out, B, F);
}

// Round 15
// 33.015 us; speedup vs baseline: 2.2840x; 2.2840x over previous
//
#include <hip/hip_runtime.h>

#define ISZ 128
#define HW (ISZ * ISZ)
#define TSZ 4
#define NEARP 0.1f
#define FARP 100.0f
#define EPSF 1e-9f

// d_ws layout:
//   float4 bbox[B*F]                  (umin,umax,vmin,vmax)      32 KB
//   float4 data[B*F*4]                4-float4 face record      128 KB
//   u64    keys[B*HW]                 (zp_bits<<32)|face        256 KB
// data record:
//   d0 = {c00, c01, c02, c10}
//   d1 = {c11, c12, c20, c21}
//   d2 = {c22, z0,  z1,  z2 }
//   d3 = {light, 0, 0, 0}   (only resolve reads d3)

__global__ void face_pre(const float* __restrict__ T,
                         const float* __restrict__ verts,
                         const int* __restrict__ faces,
                         const float* __restrict__ Km,
                         const float* __restrict__ dist,
                         float4* __restrict__ bbox,
                         float4* __restrict__ data,
                         unsigned long long* __restrict__ keys,
                         int B, int V, int F) {
#pragma clang fp contract(off)
    int t = blockIdx.x * blockDim.x + threadIdx.x;

    // fused keys init (grid-stride): sentinel = no hit
    int nk = B * HW;
    int stride = gridDim.x * blockDim.x;
    for (int q = t; q < nk; q += stride) keys[q] = 0xFFFFFFFFFFFFFFFFull;

    if (t >= B * F) return;
    int b = t / F, f = t - b * F;

    const float* Tb = T + b * 16;
    const float* Kb = Km + b * 9;
    const float* Db = dist + b * 5;
    float k1 = Db[0], k2 = Db[1], p1 = Db[2], p2 = Db[3], k3 = Db[4];

    int idx0 = faces[((size_t)b * F + f) * 3 + 0];
    int idx1 = faces[((size_t)b * F + f) * 3 + 1];
    int idx2 = faces[((size_t)b * F + f) * 3 + 2];
    int idx[3] = {idx0, idx1, idx2};

    float P[3][3];
    for (int k = 0; k < 3; ++k) {
        const float* vp = verts + ((size_t)b * V + idx[k]) * 3;
        P[k][0] = vp[0]; P[k][1] = vp[1]; P[k][2] = vp[2];
    }

    // ---- lighting: n = cross(v12, v10), normalized; cos = relu(n_y) ----
    float v10x = P[0][0] - P[1][0], v10y = P[0][1] - P[1][1], v10z = P[0][2] - P[1][2];
    float v12x = P[2][0] - P[1][0], v12y = P[2][1] - P[1][1], v12z = P[2][2] - P[1][2];
    float nx = v12y * v10z - v12z * v10y;
    float ny = v12z * v10x - v12x * v10z;
    float nz = v12x * v10y - v12y * v10x;
    float norm = sqrtf((nx * nx + ny * ny) + nz * nz);
    float cosv = ny / (norm + EPSF);
    cosv = fmaxf(cosv, 0.0f);
    float light = 0.5f + 0.5f * cosv;

    // ---- project the 3 vertices (exact reference op order) ----
    float xs[3], ys[3], zs[3];
    for (int k = 0; k < 3; ++k) {
        float X = P[k][0], Y = P[k][1], Z = P[k][2];
        float vcx = ((Tb[0] * X + Tb[1] * Y) + Tb[2] * Z) + Tb[3];
        float vcy = ((Tb[4] * X + Tb[5] * Y) + Tb[6] * Z) + Tb[7];
        float vcz = ((Tb[8] * X + Tb[9] * Y) + Tb[10] * Z) + Tb[11];
        float zq = vcz + EPSF;
        float x_ = vcx / zq;
        float y_ = vcy / zq;
        float r2 = x_ * x_ + y_ * y_;
        float rad = ((1.0f + k1 * r2) + (k2 * r2) * r2) + ((k3 * r2) * r2) * r2;
        float xd = (x_ * rad + ((2.0f * p1) * x_) * y_) + p2 * (r2 + (2.0f * x_) * x_);
        float yd = (y_ * rad + p1 * (r2 + (2.0f * y_) * y_)) + ((2.0f * p2) * x_) * y_;
        float pixx = (Kb[0] * xd + Kb[1] * yd) + Kb[2];
        float pixy = (Kb[3] * xd + Kb[4] * yd) + Kb[5];
        float u = (2.0f * (pixx - (float)ISZ / 2.0f)) / (float)ISZ;
        float v = (2.0f * (((float)ISZ - pixy) - (float)ISZ / 2.0f)) / (float)ISZ;
        xs[k] = u; ys[k] = v; zs[k] = vcz;
    }

    float x0 = xs[0], x1 = xs[1], x2 = xs[2];
    float y0 = ys[0], y1 = ys[1], y2 = ys[2];

    float det = (x0 * (y1 - y2) + x1 * (y2 - y0)) + x2 * (y0 - y1);
    bool degen = fabsf(det) < 1e-6f;
    if (degen) det = 1e-6f;

    float c00 = (y1 - y2) / det, c01 = (x2 - x1) / det, c02 = (x1 * y2 - x2 * y1) / det;
    float c10 = (y2 - y0) / det, c11 = (x0 - x2) / det, c12 = (x2 * y0 - x0 * y2) / det;
    float c20 = (y0 - y1) / det, c21 = (x1 - x0) / det, c22 = (x0 * y1 - x1 * y0) / det;

    float umin, umax, vmin, vmax;
    if (degen) {
        // clamped-det faces rasterize as an unbounded thin band: scan whole image.
        umin = -1e30f; umax = 1e30f; vmin = -1e30f; vmax = 1e30f;
    } else {
        umin = fminf(fminf(x0, x1), x2) - 1e-3f;
        umax = fmaxf(fmaxf(x0, x1), x2) + 1e-3f;
        vmin = fminf(fminf(y0, y1), y2) - 1e-3f;
        vmax = fmaxf(fmaxf(y0, y1), y2) + 1e-3f;
    }

    bbox[t] = make_float4(umin, umax, vmin, vmax);
    float4* dp = data + (size_t)t * 4;
    dp[0] = make_float4(c00, c01, c02, c10);
    dp[1] = make_float4(c11, c12, c20, c21);
    dp[2] = make_float4(c22, zs[0], zs[1], zs[2]);
    dp[3] = make_float4(light, 0.0f, 0.0f, 0.0f);
}

// One 256-thread block PER FACE. Face record loaded once; 4 waves sweep the
// face's clamped bbox rows (wave w: rows w, w+4, ...; lanes = columns).
// No LDS, no candidate scan, fully independent iterations. Winner published
// via FIRE-AND-FORGET u64 atomicMin of (zp_bits<<32)|face — return value
// unused, so the wave never waits on the atomic; iterations pipeline freely.
// Bit-monotone key => exact lexicographic (zp, face) min == np.argmin
// first-occurrence, independent of execution order.
__global__ __launch_bounds__(256) void raster_face(
        const float4* __restrict__ bbox,
        const float4* __restrict__ data,
        unsigned long long* __restrict__ keys,
        int B, int F) {
#pragma clang fp contract(off)
    int blk = blockIdx.x;            // = b*F + f
    int b = blk / F, f = blk - b * F;
    int tid = threadIdx.x, wid = tid >> 6, lane = tid & 63;

    float4 bb = bbox[blk];           // umin,umax,vmin,vmax

    // pixel-center ranges: px(j) = (2j+1-128)/128 (monotone in j), same for py(i).
    // conservative outward rounding; extra pixels are harmless (exact test follows).
    float jminf = ceilf((bb.x * 128.0f + 127.0f) * 0.5f - 1e-3f);
    float jmaxf = floorf((bb.y * 128.0f + 127.0f) * 0.5f + 1e-3f);
    float iminf = ceilf((bb.z * 128.0f + 127.0f) * 0.5f - 1e-3f);
    float imaxf = floorf((bb.w * 128.0f + 127.0f) * 0.5f + 1e-3f);
    if (jminf > 127.0f || jmaxf < 0.0f || iminf > 127.0f || imaxf < 0.0f) return;
    int jmin = (int)fmaxf(jminf, 0.0f);
    int jmax = (int)fminf(jmaxf, 127.0f);
    int imin = (int)fmaxf(iminf, 0.0f);
    int imax = (int)fminf(imaxf, 127.0f);
    if (jmax < jmin || imax < imin) return;

    const float4* dp = data + (size_t)blk * 4;
    float4 d0 = dp[0], d1 = dp[1], d2 = dp[2];
    unsigned long long* kb = keys + (size_t)b * HW;
    unsigned long long fkey = (unsigned)f;

    for (int i = imin + wid; i <= imax; i += 4) {
        float py = (float)(2 * i + 1 - ISZ) / (float)ISZ;
        for (int j0 = jmin; j0 <= jmax; j0 += 64) {
            int j = j0 + lane;
            bool act = (j <= jmax);
            float px = (float)(2 * j + 1 - ISZ) / (float)ISZ;
            float w0 = (d0.x * px + d0.y * py) + d0.z;
            float w1 = (d0.w * px + d1.x * py) + d1.y;
            float w2 = (d1.z * px + d1.w * py) + d2.x;
            bool inside = act &
                          (w0 >= 0.0f) & (w0 <= 1.0f) &
                          (w1 >= 0.0f) & (w1 <= 1.0f) &
                          (w2 >= 0.0f) & (w2 <= 1.0f);
            if (__any(inside)) {
                float s = ((w0 / d2.y) + (w1 / d2.z)) + (w2 / d2.w);
                float zp = 1.0f / s;
                if (inside & (zp > NEARP) & (zp < FARP)) {
                    unsigned long long key =
                        ((unsigned long long)__float_as_uint(zp) << 32) | fkey;
                    int p = i * ISZ + j;
                    atomicMin(&kb[p], key);   // fire-and-forget: no result use
                }
            }
        }
    }
}

// One thread per pixel: read winning (zp,face), recompute shading with
// bit-identical ops (same inputs -> same IEEE results as the raster pass).
__global__ __launch_bounds__(256) void resolve(
        const unsigned long long* __restrict__ keys,
        const float4* __restrict__ data,
        const float* __restrict__ tex,
        float* __restrict__ out,
        int B, int F) {
#pragma clang fp contract(off)
    int t = blockIdx.x * blockDim.x + threadIdx.x;
    if (t >= B * HW) return;
    int b = t / HW, p = t - b * HW;
    int i = p / ISZ, j = p - i * ISZ;

    unsigned long long key = keys[t];
    float o0 = 0.0f, o1 = 0.0f, o2 = 0.0f;
    if (key != 0xFFFFFFFFFFFFFFFFull) {
        int f = (int)(unsigned)(key & 0xFFFFFFFFull);
        const float4* dp = data + ((size_t)b * F + f) * 4;
        float4 d0 = dp[0], d1 = dp[1], d2 = dp[2], d3 = dp[3];
        float px = (float)(2 * j + 1 - ISZ) / (float)ISZ;
        float py = (float)(2 * i + 1 - ISZ) / (float)ISZ;
        float w0 = (d0.x * px + d0.y * py) + d0.z;
        float w1 = (d0.w * px + d1.x * py) + d1.y;
        float w2 = (d1.z * px + d1.w * py) + d2.x;
        float z0 = d2.y, z1 = d2.z, z2 = d2.w;
        float s = ((w0 / z0) + (w1 / z1)) + (w2 / z2);
        float zp = 1.0f / s;

        float wp0 = (w0 / z0) * zp;
        float wp1 = (w1 / z1) * zp;
        float wp2 = (w2 / z2) * zp;
        wp0 = fminf(fmaxf(wp0, 0.0f), 1.0f);
        wp1 = fminf(fmaxf(wp1, 0.0f), 1.0f);
        wp2 = fminf(fmaxf(wp2, 0.0f), 1.0f);
        float ssum = ((wp0 + wp1) + wp2) + EPSF;
        wp0 = wp0 / ssum; wp1 = wp1 / ssum; wp2 = wp2 / ssum;
        int t0 = min(max((int)floorf(wp0 * (float)TSZ), 0), TSZ - 1);
        int t1 = min(max((int)floorf(wp1 * (float)TSZ), 0), TSZ - 1);
        int t2c = min(max((int)floorf(wp2 * (float)TSZ), 0), TSZ - 1);
        float light = d3.x;
        const float* tp = tex + ((((((size_t)b * F + f) * TSZ + t0) * TSZ + t1) * TSZ + t2c) * 3);
        o0 = tp[0] * light;
        o1 = tp[1] * light;
        o2 = tp[2] * light;
    }

    out[((size_t)b * 3 + 0) * HW + p] = o0;
    out[((size_t)b * 3 + 1) * HW + p] = o1;
    out[((size_t)b * 3 + 2) * HW + p] = o2;
}

extern "C" void kernel_launch(void* const* d_in, const int* in_sizes, int n_in,
                              void* d_out, int out_size, void* d_ws, size_t ws_size,
                              hipStream_t stream) {
    const float* T     = (const float*)d_in[0];
    const float* verts = (const float*)d_in[1];
    const int*   faces = (const int*)d_in[2];
    const float* tex   = (const float*)d_in[3];
    const float* Km    = (const float*)d_in[4];
    const float* dist  = (const float*)d_in[5];

    int B = in_sizes[0] / 16;
    int V = in_sizes[1] / (3 * B);
    int F = in_sizes[2] / (3 * B);

    float4* bbox = (float4*)d_ws;                        // B*F float4
    float4* data = bbox + (size_t)B * F;                 // B*F*4 float4
    unsigned long long* keys =
        (unsigned long long*)(data + (size_t)B * F * 4); // B*HW u64

    int nfaces = B * F;
    face_pre<<<(nfaces + 255) / 256, 256, 0, stream>>>(T, verts, faces, Km, dist,
                                                       bbox, data, keys, B, V, F);

    raster_face<<<nfaces, 256, 0, stream>>>(bbox, data, keys, B, F);

    int npix = B * HW;
    resolve<<<(npix + 255) / 256, 256, 0, stream>>>(keys, data, tex,
                                                    (float*)d_out, B, F);
}